// Round 1
// baseline (49.500 us; speedup 1.0000x reference)
//
#include <hip/hip_runtime.h>
#include <math.h>

#define BS 16
#define NQ 100
#define NPTS 25
#define VOC 96
#define NC (VOC + 1)       // 97 classes incl. padding
#define MAXLEN 25
#define NGT 32
#define EDIM 300
#define NCOL (BS * NGT)    // 512
#define NDIM (NPTS * 2)    // 50
#define TQ 10              // queries per assemble block (divides NQ)

// ---------------- workspace layout (floats) ----------------
#define WS_GRAM 0                                   // VOC*VOC = 9216
#define WS_TGTS (WS_GRAM + VOC * VOC)               // BS*NGT*VOC = 49152
#define WS_NEGENT (WS_TGTS + BS * NGT * VOC)        // BS*NGT = 512
#define WS_LOGP (WS_NEGENT + BS * NGT)              // BS*NQ*VOC = 153600
#define WS_CC (WS_LOGP + BS * NQ * VOC)             // BS*NQ = 1600
#define WS_TGTT (WS_CC + BS * NQ)                   // NDIM*NCOL = 25600

// ---- Kernel A: Gram softmax table: gram[v][c] = softmax_c( dot(cen[v],cen[c]) / sqrt(EDIM) )
__global__ void gram_kernel(const float* __restrict__ cen, float* __restrict__ gram) {
    int v = blockIdx.x;
    int tid = threadIdx.x;           // 128 threads
    __shared__ float row[EDIM];
    __shared__ float red[128];
    for (int k = tid; k < EDIM; k += 128) row[k] = cen[v * EDIM + k];
    __syncthreads();
    float val = -INFINITY;
    if (tid < VOC) {
        float acc = 0.f;
        const float* c = cen + (size_t)tid * EDIM;
        for (int k = 0; k < EDIM; ++k) acc += row[k] * c[k];
        val = acc * (1.0f / sqrtf((float)EDIM));
    }
    red[tid] = val;
    __syncthreads();
    for (int s = 64; s > 0; s >>= 1) { if (tid < s) red[tid] = fmaxf(red[tid], red[tid + s]); __syncthreads(); }
    float m = red[0];
    __syncthreads();
    float e = (tid < VOC) ? expf(val - m) : 0.f;
    red[tid] = e;
    __syncthreads();
    for (int s = 64; s > 0; s >>= 1) { if (tid < s) red[tid] += red[tid + s]; __syncthreads(); }
    if (tid < VOC) gram[v * VOC + tid] = e / red[0];
}

// ---- Kernel B: per (b,g): tgt_s (normalized) and neg_ent; len==0 encoded as tgt_s=0, neg_ent=100
__global__ void tgt_kernel(const int* __restrict__ texts, const float* __restrict__ gram,
                           float* __restrict__ tgt_s, float* __restrict__ neg_ent) {
    int bg = blockIdx.x;             // 0..511
    int tid = threadIdx.x;           // 128
    __shared__ int idx[MAXLEN];
    __shared__ float red[128];
    __shared__ int slen;
    if (tid < MAXLEN) idx[tid] = texts[bg * MAXLEN + tid];
    __syncthreads();
    if (tid == 0) { int l = 0; for (int i = 0; i < MAXLEN; ++i) if (idx[i] != VOC) ++l; slen = l; }
    __syncthreads();
    int len = slen;
    float t = 0.f;
    if (tid < VOC) {
        float acc = 0.f;
        for (int l = 0; l < MAXLEN; ++l) {
            int v = idx[l];
            if (v != VOC) acc += gram[v * VOC + tid];
        }
        float avg = acc / (float)(len > 0 ? len : 1);
        t = fmaxf(avg, 1e-6f);
    }
    red[tid] = t;
    __syncthreads();
    for (int s = 64; s > 0; s >>= 1) { if (tid < s) red[tid] += red[tid + s]; __syncthreads(); }
    float tsum = red[0];
    __syncthreads();
    float ts = (tid < VOC) ? t / tsum : 0.f;
    float contrib = (tid < VOC) ? ts * logf(ts) : 0.f;
    red[tid] = contrib;
    __syncthreads();
    for (int s = 64; s > 0; s >>= 1) { if (tid < s) red[tid] += red[tid + s]; __syncthreads(); }
    if (tid < VOC) tgt_s[(size_t)bg * VOC + tid] = (len == 0) ? 0.f : ts;
    if (tid == 0) neg_ent[bg] = (len == 0) ? 100.f : red[0];
}

// ---- Kernel C: per (b,q): logp[c] = log(max(mean_p softmax(logits)[c], eps)); focal cost_class
__global__ void pred_kernel(const float* __restrict__ logits1,   // (bq,25,1)
                            const float* __restrict__ tlogits,   // (bq,25,97)
                            float* __restrict__ logp, float* __restrict__ cost_class) {
    int bq = blockIdx.x;             // 0..1599
    int tid = threadIdx.x;           // 128 = 2 waves
    __shared__ float sh[NPTS * NC];  // 2425 floats
    __shared__ float pmax[NPTS], pinv[NPTS];
    const float* src = tlogits + (size_t)bq * NPTS * NC;
    for (int i = tid; i < NPTS * NC; i += 128) sh[i] = src[i];
    __syncthreads();
    int wave = tid >> 6, lane = tid & 63;
    for (int p = wave; p < NPTS; p += 2) {
        const float* r = sh + p * NC;
        float x0 = r[lane];
        float x1 = (lane < NC - 64) ? r[lane + 64] : -INFINITY;
        float m = fmaxf(x0, x1);
        for (int o = 32; o > 0; o >>= 1) m = fmaxf(m, __shfl_xor(m, o));
        float e = expf(x0 - m) + ((lane < NC - 64) ? expf(x1 - m) : 0.f);
        for (int o = 32; o > 0; o >>= 1) e += __shfl_xor(e, o);
        if (lane == 0) { pmax[p] = m; pinv[p] = 1.f / e; }
    }
    __syncthreads();
    if (tid < VOC) {
        float acc = 0.f;
        for (int p = 0; p < NPTS; ++p) acc += expf(sh[p * NC + tid] - pmax[p]) * pinv[p];
        float avg = acc / (float)NPTS;
        logp[(size_t)bq * VOC + tid] = logf(fmaxf(avg, 1e-6f));
    }
    if (wave == 0) {
        float sig = 0.f;
        if (lane < NPTS) { float x = logits1[bq * NPTS + lane]; sig = 1.f / (1.f + expf(-x)); }
        for (int o = 32; o > 0; o >>= 1) sig += __shfl_xor(sig, o);
        if (lane == 0) {
            float prob = sig / (float)NPTS;
            float negc = 0.75f * prob * prob * (-logf(1.f - prob + 1e-8f));
            float posc = 0.25f * (1.f - prob) * (1.f - prob) * (-logf(prob + 1e-8f));
            cost_class[bq] = posc - negc;
        }
    }
}

// ---- Kernel D: transpose tgt points (512,50) -> (50,512) for coalesced reads
__global__ void transpose_pts(const float* __restrict__ in, float* __restrict__ outT) {
    int g = blockIdx.x * 256 + threadIdx.x;
    if (g < NCOL * NDIM) {
        int k = g / NCOL;
        int j = g - k * NCOL;
        outT[g] = in[(size_t)j * NDIM + k];
    }
}

// ---- Kernel E: assemble C[bq][col] = cost_class + L1 + blockdiag KL, TQ queries per block
__global__ void assemble_kernel(const float* __restrict__ pred_pts,
                                const float* __restrict__ tgtT,
                                const float* __restrict__ tgt_s,
                                const float* __restrict__ neg_ent,
                                const float* __restrict__ logp,
                                const float* __restrict__ cost_class,
                                float* __restrict__ out) {
    int bq0 = blockIdx.x * TQ;       // grid = 160
    int b = bq0 / NQ;                // TQ | NQ so whole block is one b
    int tid = threadIdx.x;           // 512
    __shared__ float pp[TQ][NDIM];
    __shared__ float lp[TQ][VOC];
    __shared__ float cc[TQ];
    __shared__ float ct[TQ][NGT];
    for (int i = tid; i < TQ * NDIM; i += 512) pp[i / NDIM][i % NDIM] = pred_pts[(size_t)bq0 * NDIM + i];
    for (int i = tid; i < TQ * VOC; i += 512) lp[i / VOC][i % VOC] = logp[(size_t)bq0 * VOC + i];
    if (tid < TQ) cc[tid] = cost_class[bq0 + tid];
    __syncthreads();
    if (tid < TQ * NGT) {
        int q = tid / NGT, g = tid % NGT;
        const float* ts = tgt_s + (size_t)(b * NGT + g) * VOC;
        float dot = 0.f;
        for (int c = 0; c < VOC; ++c) dot += lp[q][c] * ts[c];
        ct[q][g] = fmaxf(neg_ent[b * NGT + g] - dot, 0.f);
    }
    __syncthreads();
    float acc[TQ];
#pragma unroll
    for (int q = 0; q < TQ; ++q) acc[q] = 0.f;
    for (int k = 0; k < NDIM; ++k) {
        float tv = tgtT[k * NCOL + tid];
#pragma unroll
        for (int q = 0; q < TQ; ++q) acc[q] += fabsf(pp[q][k] - tv);
    }
    int inb = ((tid >> 5) == b);
    int g = tid & 31;
#pragma unroll
    for (int q = 0; q < TQ; ++q) {
        float text = inb ? ct[q][g] : 0.f;
        out[(size_t)(bq0 + q) * NCOL + tid] = cc[q] + acc[q] + text;
    }
}

extern "C" void kernel_launch(void* const* d_in, const int* in_sizes, int n_in,
                              void* d_out, int out_size, void* d_ws, size_t ws_size,
                              hipStream_t stream) {
    const float* pred_logits      = (const float*)d_in[0];
    const float* pred_ctrl_points = (const float*)d_in[1];
    const float* pred_text_logits = (const float*)d_in[2];
    const float* tgt_ctrl_points  = (const float*)d_in[3];
    const int*   target_texts     = (const int*)d_in[4];
    const float* centroids        = (const float*)d_in[5];
    float* out = (float*)d_out;
    float* ws = (float*)d_ws;

    float* gram   = ws + WS_GRAM;
    float* tgts   = ws + WS_TGTS;
    float* negent = ws + WS_NEGENT;
    float* logp   = ws + WS_LOGP;
    float* cc     = ws + WS_CC;
    float* tgtT   = ws + WS_TGTT;

    gram_kernel<<<VOC, 128, 0, stream>>>(centroids, gram);
    tgt_kernel<<<BS * NGT, 128, 0, stream>>>(target_texts, gram, tgts, negent);
    pred_kernel<<<BS * NQ, 128, 0, stream>>>(pred_logits, pred_text_logits, logp, cc);
    transpose_pts<<<(NCOL * NDIM + 255) / 256, 256, 0, stream>>>(tgt_ctrl_points, tgtT);
    assemble_kernel<<<(BS * NQ) / TQ, 512, 0, stream>>>(pred_ctrl_points, tgtT, tgts, negent,
                                                        logp, cc, out);
}